// Round 1
// baseline (317.064 us; speedup 1.0000x reference)
//
#include <hip/hip_runtime.h>
#include <hip/hip_bf16.h>
#include <cstdint>
#include <cstddef>

// B=2, S=2048, D=1024, H=16, HD=64
// softmax is over the HEAD axis (axis=1): attn[b,h,q,k] = exp(s)/sum_h' exp(s)
//
// Pipeline:
//  1. cast x, Wq, Wk, Wv, Wo to bf16
//  2. Q/K/V = gemm_bt(xb, W*) -> bf16 (4096 x 1024 row-major, col = h*64+d)
//  3. Vt = transpose(V): Vt[c*4096 + m]  (contiguous along token for PV MFMA B-operand)
//  4. rd[b,q,k] = bf16(1 / sum_h exp(s/8))   (recompute QK^T per head)
//  5. AO[b,q,h*64+d] = sum_k exp(s/8)*rd * V  (per (b,h,qtile): recompute QK^T,
//     P roundtrip through LDS C-layout -> A-layout)
//  6. out = gemm_bt(AO, Wo) + bo -> fp32 d_out

typedef __bf16 bf16x8 __attribute__((ext_vector_type(8)));
typedef __bf16 bf16x4 __attribute__((ext_vector_type(4)));
typedef float floatx4 __attribute__((ext_vector_type(4)));

#define S_LEN 2048
#define DIM 1024
#define NH 16
#define HD 64
#define MTOT 4096  // B * S

// ---------------- cast fp32 -> bf16 ----------------
__global__ void cast_f32_bf16(const float* __restrict__ s, __bf16* __restrict__ d, int n) {
    int i = (blockIdx.x * blockDim.x + threadIdx.x) * 4;
    if (i < n) {
        float4 v = *(const float4*)&s[i];
        bf16x4 o;
        o.x = (__bf16)v.x; o.y = (__bf16)v.y; o.z = (__bf16)v.z; o.w = (__bf16)v.w;
        *(bf16x4*)&d[i] = o;
    }
}

// ---------------- GEMM: C[m,n] = sum_k A[m,k]*Bw[n,k] + bias[n] ----------------
// A: (M,K) bf16 row-major, Bw: (N,K) bf16 row-major. 128x128 tile, BK=32, 4 waves.
template <typename OUT_T>
__global__ __launch_bounds__(256, 2) void gemm_bt(const __bf16* __restrict__ A,
                                                  const __bf16* __restrict__ Bw,
                                                  const float* __restrict__ bias,
                                                  OUT_T* __restrict__ C,
                                                  int M, int N, int K) {
    const int tm = blockIdx.y * 128;
    const int tn = blockIdx.x * 128;
    __shared__ __bf16 As[128 * 40];  // stride 40 elems = 80B (16B-aligned rows, banks spread)
    __shared__ __bf16 Bs[128 * 40];
    const int tid = threadIdx.x;
    const int wid = tid >> 6, lane = tid & 63;
    const int wm = (wid >> 1) * 64, wn = (wid & 1) * 64;
    const int l15 = lane & 15, quad = lane >> 4;
    floatx4 acc[4][4] = {};
    for (int k0 = 0; k0 < K; k0 += 32) {
        __syncthreads();
#pragma unroll
        for (int i = 0; i < 2; ++i) {
            int c = i * 256 + tid;            // 0..511
            int row = c >> 2, kc = (c & 3) * 8;
            *(bf16x8*)&As[row * 40 + kc] = *(const bf16x8*)&A[(size_t)(tm + row) * K + k0 + kc];
            *(bf16x8*)&Bs[row * 40 + kc] = *(const bf16x8*)&Bw[(size_t)(tn + row) * K + k0 + kc];
        }
        __syncthreads();
        bf16x8 af[4], bf[4];
#pragma unroll
        for (int t = 0; t < 4; ++t) {
            af[t] = *(const bf16x8*)&As[(wm + t * 16 + l15) * 40 + quad * 8];
            bf[t] = *(const bf16x8*)&Bs[(wn + t * 16 + l15) * 40 + quad * 8];
        }
#pragma unroll
        for (int im = 0; im < 4; ++im)
#pragma unroll
            for (int in = 0; in < 4; ++in)
                acc[im][in] = __builtin_amdgcn_mfma_f32_16x16x32_bf16(af[im], bf[in], acc[im][in], 0, 0, 0);
    }
#pragma unroll
    for (int im = 0; im < 4; ++im)
#pragma unroll
        for (int in = 0; in < 4; ++in)
#pragma unroll
            for (int r = 0; r < 4; ++r) {
                int row = tm + wm + im * 16 + quad * 4 + r;   // C layout: row = quad*4+reg
                int col = tn + wn + in * 16 + l15;            //            col = lane&15
                float v = acc[im][in][r] + bias[col];
                C[(size_t)row * N + col] = (OUT_T)v;
            }
}

// ---------------- transpose (M,N) -> (N,M), bf16 ----------------
__global__ void transpose_bf16(const __bf16* __restrict__ src, __bf16* __restrict__ dst,
                               int M, int N) {
    __shared__ __bf16 t[32][33];
    int bx = blockIdx.x * 32;  // col tile
    int by = blockIdx.y * 32;  // row tile
    int x = threadIdx.x, y = threadIdx.y;  // 32 x 8
#pragma unroll
    for (int i = 0; i < 32; i += 8) t[y + i][x] = src[(size_t)(by + y + i) * N + bx + x];
    __syncthreads();
#pragma unroll
    for (int i = 0; i < 32; i += 8) dst[(size_t)(bx + y + i) * M + by + x] = t[x][y + i];
}

// ---------------- pass 1: rd[b,q,k] = 1 / sum_h exp(s/8), bf16 ----------------
__global__ __launch_bounds__(256, 2) void den_kernel(const __bf16* __restrict__ Q,
                                                     const __bf16* __restrict__ Km,
                                                     __bf16* __restrict__ rd) {
    const int b = blockIdx.z, qt = blockIdx.y * 128, kt = blockIdx.x * 128;
    __shared__ __bf16 Qs[128 * 72];  // stride 72 (144B rows)
    __shared__ __bf16 Ks[128 * 72];
    const int tid = threadIdx.x;
    const int wid = tid >> 6, lane = tid & 63;
    const int wm = (wid >> 1) * 64, wn = (wid & 1) * 64;
    const int l15 = lane & 15, quad = lane >> 4;
    float den[4][4][4] = {};
    const size_t qbase = ((size_t)b * S_LEN + qt) * DIM;
    const size_t kbase = ((size_t)b * S_LEN + kt) * DIM;
    for (int h = 0; h < NH; ++h) {
        __syncthreads();
#pragma unroll
        for (int i = 0; i < 4; ++i) {
            int c = i * 256 + tid;          // 0..1023
            int row = c >> 3, kc = (c & 7) * 8;
            *(bf16x8*)&Qs[row * 72 + kc] = *(const bf16x8*)&Q[qbase + (size_t)row * DIM + h * HD + kc];
            *(bf16x8*)&Ks[row * 72 + kc] = *(const bf16x8*)&Km[kbase + (size_t)row * DIM + h * HD + kc];
        }
        __syncthreads();
        floatx4 acc[4][4] = {};
#pragma unroll
        for (int kc = 0; kc < 2; ++kc) {
            bf16x8 af[4], bf[4];
#pragma unroll
            for (int t = 0; t < 4; ++t) {
                af[t] = *(const bf16x8*)&Qs[(wm + t * 16 + l15) * 72 + kc * 32 + quad * 8];
                bf[t] = *(const bf16x8*)&Ks[(wn + t * 16 + l15) * 72 + kc * 32 + quad * 8];
            }
#pragma unroll
            for (int im = 0; im < 4; ++im)
#pragma unroll
                for (int in = 0; in < 4; ++in)
                    acc[im][in] = __builtin_amdgcn_mfma_f32_16x16x32_bf16(af[im], bf[in], acc[im][in], 0, 0, 0);
        }
#pragma unroll
        for (int im = 0; im < 4; ++im)
#pragma unroll
            for (int in = 0; in < 4; ++in)
#pragma unroll
                for (int r = 0; r < 4; ++r)
                    den[im][in][r] += __expf(acc[im][in][r] * 0.125f);
    }
#pragma unroll
    for (int im = 0; im < 4; ++im)
#pragma unroll
        for (int in = 0; in < 4; ++in)
#pragma unroll
            for (int r = 0; r < 4; ++r) {
                int row = qt + wm + im * 16 + quad * 4 + r;
                int col = kt + wn + in * 16 + l15;
                rd[((size_t)b * S_LEN + row) * S_LEN + col] = (__bf16)(1.0f / den[im][in][r]);
            }
}

// ---------------- pass 2: AO = sum_k (exp(s/8)*rd) * V ----------------
// grid: (qt 16, h 16, b 2). Per block: 128 q rows, one head.
__global__ __launch_bounds__(256, 2) void attn_kernel(const __bf16* __restrict__ Q,
                                                      const __bf16* __restrict__ Km,
                                                      const __bf16* __restrict__ Vt,
                                                      const __bf16* __restrict__ rd,
                                                      __bf16* __restrict__ AO) {
    const int qt = blockIdx.x * 128, h = blockIdx.y, b = blockIdx.z;
    __shared__ __bf16 KV[128 * 72];    // Ks (128x72) in phase 1, Vts (64 x stride136 = 8704) in phase 2
    __shared__ __bf16 Ps[128 * 136];   // rd tile, then P in A-layout-readable form
    const int tid = threadIdx.x;
    const int wid = tid >> 6, lane = tid & 63;
    const int wm = (wid >> 1) * 64, wn = (wid & 1) * 64;
    const int l15 = lane & 15, quad = lane >> 4;
    const size_t qrow0 = (size_t)b * S_LEN + qt;
    // Q fragments for this wave's 64 q-rows, held in registers for the whole kernel
    bf16x8 qf[4][2];
#pragma unroll
    for (int im = 0; im < 4; ++im)
#pragma unroll
        for (int kc = 0; kc < 2; ++kc)
            qf[im][kc] = *(const bf16x8*)&Q[(qrow0 + wm + im * 16 + l15) * DIM + h * HD + kc * 32 + quad * 8];
    floatx4 oacc[2][4] = {};  // PV: q rows wid*32 + im2*16, hd cols n*16
    const size_t kbase = ((size_t)b * S_LEN) * DIM;
    for (int kt = 0; kt < S_LEN; kt += 128) {
        __syncthreads();
        // stage K tile (rows kt..kt+127 of head h), stride 72
#pragma unroll
        for (int i = 0; i < 4; ++i) {
            int c = i * 256 + tid;
            int row = c >> 3, kc = (c & 7) * 8;
            *(bf16x8*)&KV[row * 72 + kc] = *(const bf16x8*)&Km[kbase + (size_t)(kt + row) * DIM + h * HD + kc];
        }
        // stage rd tile into Ps (128 x 128, stride 136)
#pragma unroll
        for (int i = 0; i < 8; ++i) {
            int c = i * 256 + tid;         // 0..2047
            int row = c >> 4, cc = (c & 15) * 8;
            *(bf16x8*)&Ps[row * 136 + cc] =
                *(const bf16x8*)&rd[((size_t)b * S_LEN + qt + row) * S_LEN + kt + cc];
        }
        __syncthreads();
        // QK^T for this (q-tile, k-tile), per wave 64x64
        floatx4 acc[4][4] = {};
#pragma unroll
        for (int kc = 0; kc < 2; ++kc) {
            bf16x8 bfr[4];
#pragma unroll
            for (int t = 0; t < 4; ++t)
                bfr[t] = *(const bf16x8*)&KV[(wn + t * 16 + l15) * 72 + kc * 32 + quad * 8];
#pragma unroll
            for (int im = 0; im < 4; ++im)
#pragma unroll
                for (int in = 0; in < 4; ++in)
                    acc[im][in] = __builtin_amdgcn_mfma_f32_16x16x32_bf16(qf[im][kc], bfr[in], acc[im][in], 0, 0, 0);
        }
        // p = exp(s/8) * rd, written back into Ps in place (each slot read+written by same lane)
#pragma unroll
        for (int im = 0; im < 4; ++im)
#pragma unroll
            for (int in = 0; in < 4; ++in)
#pragma unroll
                for (int r = 0; r < 4; ++r) {
                    int row = wm + im * 16 + quad * 4 + r;
                    int col = wn + in * 16 + l15;
                    float rdv = (float)Ps[row * 136 + col];
                    float p = __expf(acc[im][in][r] * 0.125f) * rdv;
                    Ps[row * 136 + col] = (__bf16)p;
                }
        __syncthreads();
        // stage V^T tile into KV: rows d (64), 128 keys, stride 136
#pragma unroll
        for (int i = 0; i < 4; ++i) {
            int c = i * 256 + tid;          // 0..1023
            int row = c >> 4, cc = (c & 15) * 8;
            *(bf16x8*)&KV[row * 136 + cc] =
                *(const bf16x8*)&Vt[((size_t)h * HD + row) * MTOT + b * S_LEN + kt + cc];
        }
        __syncthreads();
        // PV: each wave 32 q-rows x 64 hd
        const int qr = wid * 32;
#pragma unroll
        for (int kc = 0; kc < 4; ++kc) {
            bf16x8 pa[2], vb[4];
#pragma unroll
            for (int t = 0; t < 2; ++t)
                pa[t] = *(const bf16x8*)&Ps[(qr + t * 16 + l15) * 136 + kc * 32 + quad * 8];
#pragma unroll
            for (int t = 0; t < 4; ++t)
                vb[t] = *(const bf16x8*)&KV[(t * 16 + l15) * 136 + kc * 32 + quad * 8];
#pragma unroll
            for (int im = 0; im < 2; ++im)
#pragma unroll
                for (int n = 0; n < 4; ++n)
                    oacc[im][n] = __builtin_amdgcn_mfma_f32_16x16x32_bf16(pa[im], vb[n], oacc[im][n], 0, 0, 0);
        }
    }
    const int qr = wid * 32;
#pragma unroll
    for (int im = 0; im < 2; ++im)
#pragma unroll
        for (int n = 0; n < 4; ++n)
#pragma unroll
            for (int r = 0; r < 4; ++r) {
                int row = qt + qr + im * 16 + quad * 4 + r;
                int col = h * HD + n * 16 + l15;
                AO[((size_t)b * S_LEN + row) * DIM + col] = (__bf16)(oacc[im][n][r]);
            }
}

extern "C" void kernel_launch(void* const* d_in, const int* in_sizes, int n_in,
                              void* d_out, int out_size, void* d_ws, size_t ws_size,
                              hipStream_t stream) {
    const float* x  = (const float*)d_in[0];
    const float* Wq = (const float*)d_in[1];
    const float* bq = (const float*)d_in[2];
    const float* Wk = (const float*)d_in[3];
    const float* bk = (const float*)d_in[4];
    const float* Wv = (const float*)d_in[5];
    const float* bv = (const float*)d_in[6];
    const float* Wo = (const float*)d_in[7];
    const float* bo = (const float*)d_in[8];
    float* out = (float*)d_out;

    char* ws = (char*)d_ws;
    const size_t MB = 1u << 20;
    __bf16* xb  = (__bf16*)(ws);                 // 8 MB
    __bf16* Wqb = (__bf16*)(ws + 8 * MB);        // 2 MB
    __bf16* Wkb = (__bf16*)(ws + 10 * MB);
    __bf16* Wvb = (__bf16*)(ws + 12 * MB);
    __bf16* Wob = (__bf16*)(ws + 14 * MB);
    __bf16* Qb  = (__bf16*)(ws + 16 * MB);       // 8 MB
    __bf16* Kb  = (__bf16*)(ws + 24 * MB);       // 8 MB
    __bf16* Vb  = (__bf16*)(ws + 32 * MB);       // 8 MB
    __bf16* Vtb = (__bf16*)(ws + 40 * MB);       // 8 MB
    __bf16* rd  = (__bf16*)(ws + 48 * MB);       // 16 MB
    __bf16* AOb = (__bf16*)(ws + 64 * MB);       // 8 MB  (total 72 MB)

    // 1. casts
    cast_f32_bf16<<<4096, 256, 0, stream>>>(x,  xb,  MTOT * DIM);
    cast_f32_bf16<<<1024, 256, 0, stream>>>(Wq, Wqb, DIM * DIM);
    cast_f32_bf16<<<1024, 256, 0, stream>>>(Wk, Wkb, DIM * DIM);
    cast_f32_bf16<<<1024, 256, 0, stream>>>(Wv, Wvb, DIM * DIM);
    cast_f32_bf16<<<1024, 256, 0, stream>>>(Wo, Wob, DIM * DIM);

    // 2. Q/K/V projections
    dim3 gproj(DIM / 128, MTOT / 128);  // (8, 32)
    gemm_bt<__bf16><<<gproj, 256, 0, stream>>>(xb, Wqb, bq, Qb, MTOT, DIM, DIM);
    gemm_bt<__bf16><<<gproj, 256, 0, stream>>>(xb, Wkb, bk, Kb, MTOT, DIM, DIM);
    gemm_bt<__bf16><<<gproj, 256, 0, stream>>>(xb, Wvb, bv, Vb, MTOT, DIM, DIM);

    // 3. V transpose -> (DIM, MTOT)
    dim3 gtr(DIM / 32, MTOT / 32);  // (32, 128)
    transpose_bf16<<<gtr, dim3(32, 8), 0, stream>>>(Vb, Vtb, MTOT, DIM);

    // 4. denominators (reciprocal, bf16)
    dim3 gden(S_LEN / 128, S_LEN / 128, 2);  // (16,16,2)
    den_kernel<<<gden, 256, 0, stream>>>(Qb, Kb, rd);

    // 5. attention
    dim3 gattn(S_LEN / 128, NH, 2);  // (16,16,2)
    attn_kernel<<<gattn, 256, 0, stream>>>(Qb, Kb, Vtb, rd, AOb);

    // 6. output projection -> fp32 d_out
    gemm_bt<float><<<gproj, 256, 0, stream>>>(AOb, Wob, bo, out, MTOT, DIM, DIM);
}

// Round 2
// 310.670 us; speedup vs baseline: 1.0206x; 1.0206x over previous
//
#include <hip/hip_runtime.h>
#include <hip/hip_bf16.h>
#include <cstdint>
#include <cstddef>

// B=2, S=2048, D=1024, H=16, HD=64.  softmax over HEAD axis.
// v2: S^T-orientation attention (P stays in registers), fp16 PV via
// mfma_f32_16x16x16f16, global_load_lds staging, occupancy-tiled GEMM/den.

typedef __bf16 bf16x8 __attribute__((ext_vector_type(8)));
typedef __bf16 bf16x4 __attribute__((ext_vector_type(4)));
typedef _Float16 f16x4 __attribute__((ext_vector_type(4)));
typedef _Float16 f16x8 __attribute__((ext_vector_type(8)));
typedef float floatx4 __attribute__((ext_vector_type(4)));

#define S_LEN 2048
#define DIM 1024
#define NH 16
#define HD 64
#define MTOT 4096  // B * S

__device__ __forceinline__ void g2l16(const void* g, void* l) {
    __builtin_amdgcn_global_load_lds(
        (const __attribute__((address_space(1))) void*)g,
        (__attribute__((address_space(3))) void*)l, 16, 0, 0);
}

// ---------------- cast fp32 -> bf16 ----------------
__global__ void cast_f32_bf16(const float* __restrict__ s, __bf16* __restrict__ d, int n) {
    int i = (blockIdx.x * blockDim.x + threadIdx.x) * 4;
    if (i < n) {
        float4 v = *(const float4*)&s[i];
        bf16x4 o;
        o.x = (__bf16)v.x; o.y = (__bf16)v.y; o.z = (__bf16)v.z; o.w = (__bf16)v.w;
        *(bf16x4*)&d[i] = o;
    }
}

// ---------------- GEMM: C[m,n] = sum_k A[m,k]*Bw[n,k] + bias[n] ----------------
// 128M x 64N tile, BK=64 as two [rows][32] panels, async staging, 4 waves (64x32 each).
template <typename OUT_T>
__global__ __launch_bounds__(256, 2) void gemm_bt2(const __bf16* __restrict__ A,
                                                   const __bf16* __restrict__ Bw,
                                                   const float* __restrict__ bias,
                                                   OUT_T* __restrict__ C,
                                                   int M, int N, int K) {
    const int tm = blockIdx.y * 128, tn = blockIdx.x * 64;
    __shared__ __bf16 As[2 * 128 * 32];  // 16 KB, panel p = k-half
    __shared__ __bf16 Bs[2 * 64 * 32];   // 8 KB
    const int tid = threadIdx.x, wid = tid >> 6, lane = tid & 63;
    const int l15 = lane & 15, quad = lane >> 4;
    const int wm = (wid >> 1) * 64, wn = (wid & 1) * 32;
    floatx4 acc[4][2] = {};
    for (int k0 = 0; k0 < K; k0 += 64) {
        __syncthreads();
#pragma unroll
        for (int i = 0; i < 4; ++i) {
            int slot = i * 256 + tid;  // 0..1023
            int p = slot >> 9, r = (slot >> 2) & 127, c8 = (slot & 3) * 8;
            g2l16(&A[(size_t)(tm + r) * K + k0 + p * 32 + c8], &As[slot * 8]);
        }
#pragma unroll
        for (int i = 0; i < 2; ++i) {
            int slot = i * 256 + tid;  // 0..511
            int p = slot >> 8, r = (slot >> 2) & 63, c8 = (slot & 3) * 8;
            g2l16(&Bw[(size_t)(tn + r) * K + k0 + p * 32 + c8], &Bs[slot * 8]);
        }
        __syncthreads();
#pragma unroll
        for (int kc = 0; kc < 2; ++kc) {
            bf16x8 af[4], bf[2];
#pragma unroll
            for (int t = 0; t < 4; ++t)
                af[t] = *(const bf16x8*)&As[kc * 4096 + (wm + t * 16 + l15) * 32 + quad * 8];
#pragma unroll
            for (int t = 0; t < 2; ++t)
                bf[t] = *(const bf16x8*)&Bs[kc * 2048 + (wn + t * 16 + l15) * 32 + quad * 8];
#pragma unroll
            for (int im = 0; im < 4; ++im)
#pragma unroll
                for (int in = 0; in < 2; ++in)
                    acc[im][in] = __builtin_amdgcn_mfma_f32_16x16x32_bf16(af[im], bf[in], acc[im][in], 0, 0, 0);
        }
    }
#pragma unroll
    for (int im = 0; im < 4; ++im)
#pragma unroll
        for (int in = 0; in < 2; ++in)
#pragma unroll
            for (int r = 0; r < 4; ++r) {
                int row = tm + wm + im * 16 + quad * 4 + r;
                int col = tn + wn + in * 16 + l15;
                C[(size_t)row * N + col] = (OUT_T)(acc[im][in][r] + bias[col]);
            }
}

// ---------------- transpose (M,N) -> (N,M), 16-bit ----------------
__global__ void transpose16(const ushort* __restrict__ src, ushort* __restrict__ dst,
                            int M, int N) {
    __shared__ ushort t[32][33];
    int bx = blockIdx.x * 32, by = blockIdx.y * 32;
    int x = threadIdx.x, y = threadIdx.y;  // 32 x 8
#pragma unroll
    for (int i = 0; i < 32; i += 8) t[y + i][x] = src[(size_t)(by + y + i) * N + bx + x];
    __syncthreads();
#pragma unroll
    for (int i = 0; i < 32; i += 8) dst[(size_t)(bx + y + i) * M + by + x] = t[x][y + i];
}

// ---------------- pass 1: rd[b,q,k] = 1 / sum_h exp(s/8) ----------------
// tile 64q x 128k, grid (16,32,2)=1024 blocks -> 4 blocks/CU.
__global__ __launch_bounds__(256, 4) void den2(const __bf16* __restrict__ Q,
                                               const __bf16* __restrict__ Km,
                                               __bf16* __restrict__ rd) {
    const int kt = blockIdx.x * 128, qt = blockIdx.y * 64, b = blockIdx.z;
    __shared__ __bf16 Qs[2 * 64 * 32];   // 8 KB, panels
    __shared__ __bf16 Ks[2 * 128 * 32];  // 16 KB, panels
    const int tid = threadIdx.x, wid = tid >> 6, lane = tid & 63;
    const int l15 = lane & 15, quad = lane >> 4;
    const int wq = wid * 16;  // one 16-row m-tile per wave
    floatx4 dsum[8] = {};
    for (int h = 0; h < NH; ++h) {
        __syncthreads();
#pragma unroll
        for (int i = 0; i < 2; ++i) {
            int slot = i * 256 + tid;  // 0..511
            int p = slot >> 8, r = (slot >> 2) & 63, c8 = (slot & 3) * 8;
            g2l16(&Q[(size_t)(b * S_LEN + qt + r) * DIM + h * HD + p * 32 + c8], &Qs[slot * 8]);
        }
#pragma unroll
        for (int i = 0; i < 4; ++i) {
            int slot = i * 256 + tid;  // 0..1023
            int p = slot >> 9, r = (slot >> 2) & 127, c8 = (slot & 3) * 8;
            g2l16(&Km[(size_t)(b * S_LEN + kt + r) * DIM + h * HD + p * 32 + c8], &Ks[slot * 8]);
        }
        __syncthreads();
        bf16x8 af0 = *(const bf16x8*)&Qs[(wq + l15) * 32 + quad * 8];
        bf16x8 af1 = *(const bf16x8*)&Qs[2048 + (wq + l15) * 32 + quad * 8];
#pragma unroll
        for (int n = 0; n < 8; ++n) {
            bf16x8 b0 = *(const bf16x8*)&Ks[(n * 16 + l15) * 32 + quad * 8];
            bf16x8 b1 = *(const bf16x8*)&Ks[4096 + (n * 16 + l15) * 32 + quad * 8];
            floatx4 acc = {};
            acc = __builtin_amdgcn_mfma_f32_16x16x32_bf16(af0, b0, acc, 0, 0, 0);
            acc = __builtin_amdgcn_mfma_f32_16x16x32_bf16(af1, b1, acc, 0, 0, 0);
#pragma unroll
            for (int r = 0; r < 4; ++r) dsum[n][r] += __expf(acc[r] * 0.125f);
        }
    }
#pragma unroll
    for (int n = 0; n < 8; ++n)
#pragma unroll
        for (int r = 0; r < 4; ++r) {
            int q = qt + wq + quad * 4 + r;
            int k = kt + n * 16 + l15;
            rd[(size_t)(b * S_LEN + q) * S_LEN + k] = (__bf16)(1.0f / dsum[n][r]);
        }
}

// ---------------- pass 2: AO = sum_k (exp(s/8)*rd) * V ----------------
// S^T orientation: QK^T computed as K·Q^T so P exits in the A-operand layout
// of mfma_f32_16x16x16f16 (m=l15, k=quad*4+j) — no LDS roundtrip for P.
__global__ __launch_bounds__(256, 2) void attn2(const __bf16* __restrict__ Q,
                                                const __bf16* __restrict__ Km,
                                                const _Float16* __restrict__ Vt,
                                                const __bf16* __restrict__ rd,
                                                __bf16* __restrict__ AO) {
    const int qt = blockIdx.x * 128, h = blockIdx.y, b = blockIdx.z;
    __shared__ __bf16 Ks[2 * 128 * 32];   // 16 KB, panels [kc][ktok][32]
    __shared__ __bf16 rds[128 * 136];     // 34 KB, [q][k] padded
    __shared__ _Float16 Vts[64 * 136];    // 17 KB, [d][k] padded
    const int tid = threadIdx.x, wid = tid >> 6, lane = tid & 63;
    const int l15 = lane & 15, quad = lane >> 4;
    const int wq = wid * 32;  // 32 q-rows per wave
    // Q fragments (B-operand of S^T mfma), register-resident
    bf16x8 qf[2][2];
#pragma unroll
    for (int np = 0; np < 2; ++np)
#pragma unroll
        for (int kc = 0; kc < 2; ++kc)
            qf[np][kc] = *(const bf16x8*)&Q[(size_t)(b * S_LEN + qt + wq + np * 16 + l15) * DIM +
                                            h * HD + kc * 32 + quad * 8];
    floatx4 oacc[2][4] = {};
    for (int kt = 0; kt < S_LEN; kt += 128) {
        __syncthreads();
        // K tile: async, panel layout
#pragma unroll
        for (int i = 0; i < 4; ++i) {
            int slot = i * 256 + tid;
            int p = slot >> 9, r = (slot >> 2) & 127, c8 = (slot & 3) * 8;
            g2l16(&Km[(size_t)(b * S_LEN + kt + r) * DIM + h * HD + p * 32 + c8], &Ks[slot * 8]);
        }
        // rd tile: vector stage, padded
#pragma unroll
        for (int i = 0; i < 8; ++i) {
            int slot = i * 256 + tid;  // 0..2047
            int r = slot >> 4, c = (slot & 15) * 8;
            *(bf16x8*)&rds[r * 136 + c] =
                *(const bf16x8*)&rd[(size_t)(b * S_LEN + qt + r) * S_LEN + kt + c];
        }
        // V^T tile: vector stage, padded
#pragma unroll
        for (int i = 0; i < 4; ++i) {
            int slot = i * 256 + tid;  // 0..1023
            int r = slot >> 4, c = (slot & 15) * 8;
            *(f16x8*)&Vts[r * 136 + c] =
                *(const f16x8*)&Vt[(size_t)(h * HD + r) * MTOT + b * S_LEN + kt + c];
        }
        __syncthreads();
#pragma unroll
        for (int mp = 0; mp < 8; ++mp) {  // 16-wide k-token blocks
            bf16x8 kf0 = *(const bf16x8*)&Ks[(mp * 16 + l15) * 32 + quad * 8];
            bf16x8 kf1 = *(const bf16x8*)&Ks[4096 + (mp * 16 + l15) * 32 + quad * 8];
            floatx4 s0 = {}, s1 = {};
            s0 = __builtin_amdgcn_mfma_f32_16x16x32_bf16(kf0, qf[0][0], s0, 0, 0, 0);
            s0 = __builtin_amdgcn_mfma_f32_16x16x32_bf16(kf1, qf[0][1], s0, 0, 0, 0);
            s1 = __builtin_amdgcn_mfma_f32_16x16x32_bf16(kf0, qf[1][0], s1, 0, 0, 0);
            s1 = __builtin_amdgcn_mfma_f32_16x16x32_bf16(kf1, qf[1][1], s1, 0, 0, 0);
            bf16x4 rv0 = *(const bf16x4*)&rds[(wq + l15) * 136 + mp * 16 + quad * 4];
            bf16x4 rv1 = *(const bf16x4*)&rds[(wq + 16 + l15) * 136 + mp * 16 + quad * 4];
            f16x4 pa0, pa1;
#pragma unroll
            for (int r = 0; r < 4; ++r) {
                pa0[r] = (_Float16)(__expf(s0[r] * 0.125f) * (float)rv0[r]);
                pa1[r] = (_Float16)(__expf(s1[r] * 0.125f) * (float)rv1[r]);
            }
#pragma unroll
            for (int n = 0; n < 4; ++n) {
                f16x4 vb = *(const f16x4*)&Vts[(n * 16 + l15) * 136 + mp * 16 + quad * 4];
                oacc[0][n] = __builtin_amdgcn_mfma_f32_16x16x16f16(pa0, vb, oacc[0][n], 0, 0, 0);
                oacc[1][n] = __builtin_amdgcn_mfma_f32_16x16x16f16(pa1, vb, oacc[1][n], 0, 0, 0);
            }
        }
    }
#pragma unroll
    for (int np = 0; np < 2; ++np)
#pragma unroll
        for (int n = 0; n < 4; ++n)
#pragma unroll
            for (int r = 0; r < 4; ++r) {
                int row = qt + wq + np * 16 + quad * 4 + r;
                int col = h * HD + n * 16 + l15;
                AO[(size_t)(b * S_LEN + row) * DIM + col] = (__bf16)oacc[np][n][r];
            }
}

extern "C" void kernel_launch(void* const* d_in, const int* in_sizes, int n_in,
                              void* d_out, int out_size, void* d_ws, size_t ws_size,
                              hipStream_t stream) {
    const float* x  = (const float*)d_in[0];
    const float* Wq = (const float*)d_in[1];
    const float* bq = (const float*)d_in[2];
    const float* Wk = (const float*)d_in[3];
    const float* bk = (const float*)d_in[4];
    const float* Wv = (const float*)d_in[5];
    const float* bv = (const float*)d_in[6];
    const float* Wo = (const float*)d_in[7];
    const float* bo = (const float*)d_in[8];
    float* out = (float*)d_out;

    char* ws = (char*)d_ws;
    const size_t MB = 1u << 20;
    __bf16*    xb  = (__bf16*)(ws);              // 8 MB
    __bf16*    Wqb = (__bf16*)(ws + 8 * MB);     // 2 MB
    __bf16*    Wkb = (__bf16*)(ws + 10 * MB);
    __bf16*    Wvb = (__bf16*)(ws + 12 * MB);
    __bf16*    Wob = (__bf16*)(ws + 14 * MB);
    __bf16*    Qb  = (__bf16*)(ws + 16 * MB);    // 8 MB
    __bf16*    Kb  = (__bf16*)(ws + 24 * MB);    // 8 MB
    _Float16*  Vh  = (_Float16*)(ws + 32 * MB);  // 8 MB
    _Float16*  VtH = (_Float16*)(ws + 40 * MB);  // 8 MB
    __bf16*    rd  = (__bf16*)(ws + 48 * MB);    // 16 MB
    __bf16*    AOb = (__bf16*)(ws + 64 * MB);    // 8 MB (total 72 MB)

    // 1. casts
    cast_f32_bf16<<<4096, 256, 0, stream>>>(x,  xb,  MTOT * DIM);
    cast_f32_bf16<<<1024, 256, 0, stream>>>(Wq, Wqb, DIM * DIM);
    cast_f32_bf16<<<1024, 256, 0, stream>>>(Wk, Wkb, DIM * DIM);
    cast_f32_bf16<<<1024, 256, 0, stream>>>(Wv, Wvb, DIM * DIM);
    cast_f32_bf16<<<1024, 256, 0, stream>>>(Wo, Wob, DIM * DIM);

    // 2. projections (grid 512 -> 2 blocks/CU)
    dim3 gproj(DIM / 64, MTOT / 128);  // (16, 32)
    gemm_bt2<__bf16><<<gproj, 256, 0, stream>>>(xb, Wqb, bq, Qb, MTOT, DIM, DIM);
    gemm_bt2<__bf16><<<gproj, 256, 0, stream>>>(xb, Wkb, bk, Kb, MTOT, DIM, DIM);
    gemm_bt2<_Float16><<<gproj, 256, 0, stream>>>(xb, Wvb, bv, Vh, MTOT, DIM, DIM);

    // 3. V transpose -> (DIM, MTOT), fp16
    dim3 gtr(DIM / 32, MTOT / 32);  // (32, 128)
    transpose16<<<gtr, dim3(32, 8), 0, stream>>>((const ushort*)Vh, (ushort*)VtH, MTOT, DIM);

    // 4. head-sum denominators
    dim3 gden(S_LEN / 128, S_LEN / 64, 2);  // (16, 32, 2)
    den2<<<gden, 256, 0, stream>>>(Qb, Kb, rd);

    // 5. attention
    dim3 gattn(S_LEN / 128, NH, 2);  // (16, 16, 2)
    attn2<<<gattn, 256, 0, stream>>>(Qb, Kb, VtH, rd, AOb);

    // 6. output projection -> fp32 d_out
    gemm_bt2<float><<<gproj, 256, 0, stream>>>(AOb, Wob, bo, out, MTOT, DIM, DIM);
}

// Round 3
// 282.372 us; speedup vs baseline: 1.1229x; 1.1002x over previous
//
#include <hip/hip_runtime.h>
#include <hip/hip_bf16.h>
#include <cstdint>
#include <cstddef>

// B=2, S=2048, D=1024, H=16, HD=64.  softmax over HEAD axis.
// v3: occupancy-focused. attn q-tile 64 (grid 1024, 4 blocks/CU), rd loaded
// direct from global (zero-reuse data out of LDS). den processes 2 heads per
// barrier-pair with direct-global Q frags. QKV projections + V-transpose fused
// into one N=3072 GEMM (grid 1536).

typedef __bf16 bf16x8 __attribute__((ext_vector_type(8)));
typedef __bf16 bf16x4 __attribute__((ext_vector_type(4)));
typedef _Float16 f16x4 __attribute__((ext_vector_type(4)));
typedef _Float16 f16x8 __attribute__((ext_vector_type(8)));
typedef float floatx4 __attribute__((ext_vector_type(4)));

#define S_LEN 2048
#define DIM 1024
#define NH 16
#define HD 64
#define MTOT 4096  // B * S

__device__ __forceinline__ void g2l16(const void* g, void* l) {
    __builtin_amdgcn_global_load_lds(
        (const __attribute__((address_space(1))) void*)g,
        (__attribute__((address_space(3))) void*)l, 16, 0, 0);
}

// ---------------- cast fp32 -> bf16 (x) ----------------
__global__ void cast_f32_bf16(const float* __restrict__ s, __bf16* __restrict__ d, int n) {
    int i = (blockIdx.x * blockDim.x + threadIdx.x) * 4;
    if (i < n) {
        float4 v = *(const float4*)&s[i];
        bf16x4 o;
        o.x = (__bf16)v.x; o.y = (__bf16)v.y; o.z = (__bf16)v.z; o.w = (__bf16)v.w;
        *(bf16x4*)&d[i] = o;
    }
}

// ---------------- fused cast of 4 weight matrices ----------------
__global__ void cast_w4(const float* __restrict__ w0, const float* __restrict__ w1,
                        const float* __restrict__ w2, const float* __restrict__ w3,
                        __bf16* __restrict__ o0, __bf16* __restrict__ o1,
                        __bf16* __restrict__ o2, __bf16* __restrict__ o3, int n) {
    const float* s; __bf16* d;
    switch (blockIdx.y) {
        case 0: s = w0; d = o0; break;
        case 1: s = w1; d = o1; break;
        case 2: s = w2; d = o2; break;
        default: s = w3; d = o3; break;
    }
    int i = (blockIdx.x * blockDim.x + threadIdx.x) * 4;
    if (i < n) {
        float4 v = *(const float4*)&s[i];
        bf16x4 o;
        o.x = (__bf16)v.x; o.y = (__bf16)v.y; o.z = (__bf16)v.z; o.w = (__bf16)v.w;
        *(bf16x4*)&d[i] = o;
    }
}

// ---------------- fused QKV projection GEMM ----------------
// C[m, ng] = sum_k x[m,k] * W[n,k] + b[n],  ng in [0,3072): block-uniform W select.
// Q,K -> bf16 row-major [m][1024]; V -> fp16 TRANSPOSED [d][m] (VtH).
__global__ __launch_bounds__(256, 4) void qkv_gemm(const __bf16* __restrict__ A,
                                                   const __bf16* __restrict__ Wq,
                                                   const __bf16* __restrict__ Wk,
                                                   const __bf16* __restrict__ Wv,
                                                   const float* __restrict__ bq,
                                                   const float* __restrict__ bk,
                                                   const float* __restrict__ bv,
                                                   __bf16* __restrict__ Qo,
                                                   __bf16* __restrict__ Ko,
                                                   _Float16* __restrict__ Vt) {
    const int tng = blockIdx.x * 64, tm = blockIdx.y * 128;
    const int wsel = tng >> 10, tn = tng & 1023;
    const __bf16* W = (wsel == 0) ? Wq : (wsel == 1) ? Wk : Wv;
    const float* bias = (wsel == 0) ? bq : (wsel == 1) ? bk : bv;
    __shared__ __bf16 As[2 * 128 * 32];  // 16 KB
    __shared__ __bf16 Bs[2 * 64 * 32];   // 8 KB
    const int tid = threadIdx.x, wid = tid >> 6, lane = tid & 63;
    const int l15 = lane & 15, quad = lane >> 4;
    const int wm = (wid >> 1) * 64, wn = (wid & 1) * 32;
    floatx4 acc[4][2] = {};
    for (int k0 = 0; k0 < DIM; k0 += 64) {
        __syncthreads();
#pragma unroll
        for (int i = 0; i < 4; ++i) {
            int slot = i * 256 + tid;
            int p = slot >> 9, r = (slot >> 2) & 127, c8 = (slot & 3) * 8;
            g2l16(&A[(size_t)(tm + r) * DIM + k0 + p * 32 + c8], &As[slot * 8]);
        }
#pragma unroll
        for (int i = 0; i < 2; ++i) {
            int slot = i * 256 + tid;
            int p = slot >> 8, r = (slot >> 2) & 63, c8 = (slot & 3) * 8;
            g2l16(&W[(size_t)(tn + r) * DIM + k0 + p * 32 + c8], &Bs[slot * 8]);
        }
        __syncthreads();
#pragma unroll
        for (int kc = 0; kc < 2; ++kc) {
            bf16x8 af[4], bf[2];
#pragma unroll
            for (int t = 0; t < 4; ++t)
                af[t] = *(const bf16x8*)&As[kc * 4096 + (wm + t * 16 + l15) * 32 + quad * 8];
#pragma unroll
            for (int t = 0; t < 2; ++t)
                bf[t] = *(const bf16x8*)&Bs[kc * 2048 + (wn + t * 16 + l15) * 32 + quad * 8];
#pragma unroll
            for (int im = 0; im < 4; ++im)
#pragma unroll
                for (int in = 0; in < 2; ++in)
                    acc[im][in] = __builtin_amdgcn_mfma_f32_16x16x32_bf16(af[im], bf[in], acc[im][in], 0, 0, 0);
        }
    }
    if (wsel < 2) {
        __bf16* O = wsel ? Ko : Qo;
#pragma unroll
        for (int im = 0; im < 4; ++im)
#pragma unroll
            for (int in = 0; in < 2; ++in)
#pragma unroll
                for (int r = 0; r < 4; ++r) {
                    int row = tm + wm + im * 16 + quad * 4 + r;
                    int col = tn + wn + in * 16 + l15;
                    O[(size_t)row * DIM + col] = (__bf16)(acc[im][in][r] + bias[col]);
                }
    } else {
        // V: transposed fp16 store, Vt[d][m]
#pragma unroll
        for (int im = 0; im < 4; ++im)
#pragma unroll
            for (int in = 0; in < 2; ++in) {
                int cv = tn + wn + in * 16 + l15;
                int row4 = tm + wm + im * 16 + quad * 4;
                float bv_ = bias[cv];
                f16x4 o;
#pragma unroll
                for (int r = 0; r < 4; ++r) o[r] = (_Float16)(acc[im][in][r] + bv_);
                *(f16x4*)&Vt[(size_t)cv * MTOT + row4] = o;
            }
    }
}

// ---------------- output projection GEMM (bf16 in, fp32 out) ----------------
__global__ __launch_bounds__(256, 2) void gemm_out(const __bf16* __restrict__ A,
                                                   const __bf16* __restrict__ Bw,
                                                   const float* __restrict__ bias,
                                                   float* __restrict__ C) {
    const int tm = blockIdx.y * 128, tn = blockIdx.x * 64;
    __shared__ __bf16 As[2 * 128 * 32];
    __shared__ __bf16 Bs[2 * 64 * 32];
    const int tid = threadIdx.x, wid = tid >> 6, lane = tid & 63;
    const int l15 = lane & 15, quad = lane >> 4;
    const int wm = (wid >> 1) * 64, wn = (wid & 1) * 32;
    floatx4 acc[4][2] = {};
    for (int k0 = 0; k0 < DIM; k0 += 64) {
        __syncthreads();
#pragma unroll
        for (int i = 0; i < 4; ++i) {
            int slot = i * 256 + tid;
            int p = slot >> 9, r = (slot >> 2) & 127, c8 = (slot & 3) * 8;
            g2l16(&A[(size_t)(tm + r) * DIM + k0 + p * 32 + c8], &As[slot * 8]);
        }
#pragma unroll
        for (int i = 0; i < 2; ++i) {
            int slot = i * 256 + tid;
            int p = slot >> 8, r = (slot >> 2) & 63, c8 = (slot & 3) * 8;
            g2l16(&Bw[(size_t)(tn + r) * DIM + k0 + p * 32 + c8], &Bs[slot * 8]);
        }
        __syncthreads();
#pragma unroll
        for (int kc = 0; kc < 2; ++kc) {
            bf16x8 af[4], bf[2];
#pragma unroll
            for (int t = 0; t < 4; ++t)
                af[t] = *(const bf16x8*)&As[kc * 4096 + (wm + t * 16 + l15) * 32 + quad * 8];
#pragma unroll
            for (int t = 0; t < 2; ++t)
                bf[t] = *(const bf16x8*)&Bs[kc * 2048 + (wn + t * 16 + l15) * 32 + quad * 8];
#pragma unroll
            for (int im = 0; im < 4; ++im)
#pragma unroll
                for (int in = 0; in < 2; ++in)
                    acc[im][in] = __builtin_amdgcn_mfma_f32_16x16x32_bf16(af[im], bf[in], acc[im][in], 0, 0, 0);
        }
    }
#pragma unroll
    for (int im = 0; im < 4; ++im)
#pragma unroll
        for (int in = 0; in < 2; ++in)
#pragma unroll
            for (int r = 0; r < 4; ++r) {
                int row = tm + wm + im * 16 + quad * 4 + r;
                int col = tn + wn + in * 16 + l15;
                C[(size_t)row * DIM + col] = acc[im][in][r] + bias[col];
            }
}

// ---------------- pass 1: rd[b,q,k] = 1 / sum_h exp(s/8) ----------------
// tile 64q x 128k, 2 heads staged per barrier-pair, Q frags direct from global.
__global__ __launch_bounds__(256, 4) void den3(const __bf16* __restrict__ Q,
                                               const __bf16* __restrict__ Km,
                                               __bf16* __restrict__ rd) {
    const int kt = blockIdx.x * 128, qt = blockIdx.y * 64, b = blockIdx.z;
    __shared__ __bf16 Ks[2 * 2 * 128 * 32];  // 32 KB: [head][panel][tok][32]
    const int tid = threadIdx.x, wid = tid >> 6, lane = tid & 63;
    const int l15 = lane & 15, quad = lane >> 4;
    const int wq = wid * 16;
    floatx4 dsum[8] = {};
    const size_t qrow = (size_t)(b * S_LEN + qt + wq + l15) * DIM;
    for (int hh = 0; hh < 8; ++hh) {
        __syncthreads();
#pragma unroll
        for (int i = 0; i < 8; ++i) {
            int slot = i * 256 + tid;  // 0..2047
            int hs = slot >> 10, rem = slot & 1023;
            int p = rem >> 9, r = (rem >> 2) & 127, c8 = (rem & 3) * 8;
            g2l16(&Km[(size_t)(b * S_LEN + kt + r) * DIM + (hh * 2 + hs) * HD + p * 32 + c8],
                  &Ks[slot * 8]);
        }
        __syncthreads();
#pragma unroll
        for (int hs = 0; hs < 2; ++hs) {
            int h = hh * 2 + hs;
            bf16x8 af0 = *(const bf16x8*)&Q[qrow + h * HD + quad * 8];
            bf16x8 af1 = *(const bf16x8*)&Q[qrow + h * HD + 32 + quad * 8];
#pragma unroll
            for (int n = 0; n < 8; ++n) {
                bf16x8 b0 = *(const bf16x8*)&Ks[hs * 8192 + (n * 16 + l15) * 32 + quad * 8];
                bf16x8 b1 = *(const bf16x8*)&Ks[hs * 8192 + 4096 + (n * 16 + l15) * 32 + quad * 8];
                floatx4 acc = {};
                acc = __builtin_amdgcn_mfma_f32_16x16x32_bf16(af0, b0, acc, 0, 0, 0);
                acc = __builtin_amdgcn_mfma_f32_16x16x32_bf16(af1, b1, acc, 0, 0, 0);
#pragma unroll
                for (int r = 0; r < 4; ++r) dsum[n][r] += __expf(acc[r] * 0.125f);
            }
        }
    }
#pragma unroll
    for (int n = 0; n < 8; ++n)
#pragma unroll
        for (int r = 0; r < 4; ++r) {
            int q = qt + wq + quad * 4 + r;
            int k = kt + n * 16 + l15;
            rd[(size_t)(b * S_LEN + q) * S_LEN + k] = (__bf16)(1.0f / dsum[n][r]);
        }
}

// ---------------- pass 2: AO = sum_k (exp(s/8)*rd) * V ----------------
// q-tile 64 (grid 1024), S^T orientation, rd direct from global.
__global__ __launch_bounds__(256, 4) void attn3(const __bf16* __restrict__ Q,
                                                const __bf16* __restrict__ Km,
                                                const _Float16* __restrict__ Vt,
                                                const __bf16* __restrict__ rd,
                                                __bf16* __restrict__ AO) {
    const int qt = blockIdx.x * 64, h = blockIdx.y, b = blockIdx.z;
    __shared__ __bf16 Ks[2 * 128 * 32];   // 16 KB
    __shared__ _Float16 Vts[64 * 136];    // 17.4 KB
    const int tid = threadIdx.x, wid = tid >> 6, lane = tid & 63;
    const int l15 = lane & 15, quad = lane >> 4;
    const int wq = wid * 16;
    // Q fragments (B-operand of S^T mfma), register-resident for whole kernel
    const size_t qrow = (size_t)(b * S_LEN + qt + wq + l15) * DIM + h * HD;
    bf16x8 qf0 = *(const bf16x8*)&Q[qrow + quad * 8];
    bf16x8 qf1 = *(const bf16x8*)&Q[qrow + 32 + quad * 8];
    const __bf16* rdrow = &rd[(size_t)(b * S_LEN + qt + wq + l15) * S_LEN];
    floatx4 oacc[4] = {};
    for (int kt = 0; kt < S_LEN; kt += 128) {
        __syncthreads();
#pragma unroll
        for (int i = 0; i < 4; ++i) {
            int slot = i * 256 + tid;
            int p = slot >> 9, r = (slot >> 2) & 127, c8 = (slot & 3) * 8;
            g2l16(&Km[(size_t)(b * S_LEN + kt + r) * DIM + h * HD + p * 32 + c8], &Ks[slot * 8]);
        }
#pragma unroll
        for (int i = 0; i < 4; ++i) {
            int slot = i * 256 + tid;
            int r = slot >> 4, c = (slot & 15) * 8;
            *(f16x8*)&Vts[r * 136 + c] =
                *(const f16x8*)&Vt[(size_t)(h * HD + r) * MTOT + b * S_LEN + kt + c];
        }
        __syncthreads();
#pragma unroll
        for (int mp = 0; mp < 8; ++mp) {
            bf16x8 kf0 = *(const bf16x8*)&Ks[(mp * 16 + l15) * 32 + quad * 8];
            bf16x8 kf1 = *(const bf16x8*)&Ks[4096 + (mp * 16 + l15) * 32 + quad * 8];
            floatx4 s = {};
            s = __builtin_amdgcn_mfma_f32_16x16x32_bf16(kf0, qf0, s, 0, 0, 0);
            s = __builtin_amdgcn_mfma_f32_16x16x32_bf16(kf1, qf1, s, 0, 0, 0);
            bf16x4 rv = *(const bf16x4*)&rdrow[kt + mp * 16 + quad * 4];
            f16x4 pa;
#pragma unroll
            for (int r = 0; r < 4; ++r)
                pa[r] = (_Float16)(__expf(s[r] * 0.125f) * (float)rv[r]);
#pragma unroll
            for (int n = 0; n < 4; ++n) {
                f16x4 vb = *(const f16x4*)&Vts[(n * 16 + l15) * 136 + mp * 16 + quad * 4];
                oacc[n] = __builtin_amdgcn_mfma_f32_16x16x16f16(pa, vb, oacc[n], 0, 0, 0);
            }
        }
    }
#pragma unroll
    for (int n = 0; n < 4; ++n)
#pragma unroll
        for (int r = 0; r < 4; ++r) {
            int row = qt + wq + quad * 4 + r;
            int col = h * HD + n * 16 + l15;
            AO[(size_t)(b * S_LEN + row) * DIM + col] = (__bf16)oacc[n][r];
        }
}

extern "C" void kernel_launch(void* const* d_in, const int* in_sizes, int n_in,
                              void* d_out, int out_size, void* d_ws, size_t ws_size,
                              hipStream_t stream) {
    const float* x  = (const float*)d_in[0];
    const float* Wq = (const float*)d_in[1];
    const float* bq = (const float*)d_in[2];
    const float* Wk = (const float*)d_in[3];
    const float* bk = (const float*)d_in[4];
    const float* Wv = (const float*)d_in[5];
    const float* bv = (const float*)d_in[6];
    const float* Wo = (const float*)d_in[7];
    const float* bo = (const float*)d_in[8];
    float* out = (float*)d_out;

    char* ws = (char*)d_ws;
    const size_t MB = 1u << 20;
    __bf16*    xb  = (__bf16*)(ws);              // 8 MB
    __bf16*    Wqb = (__bf16*)(ws + 8 * MB);     // 2 MB each
    __bf16*    Wkb = (__bf16*)(ws + 10 * MB);
    __bf16*    Wvb = (__bf16*)(ws + 12 * MB);
    __bf16*    Wob = (__bf16*)(ws + 14 * MB);
    __bf16*    Qb  = (__bf16*)(ws + 16 * MB);    // 8 MB
    __bf16*    Kb  = (__bf16*)(ws + 24 * MB);    // 8 MB
    _Float16*  VtH = (_Float16*)(ws + 32 * MB);  // 8 MB
    __bf16*    rd  = (__bf16*)(ws + 40 * MB);    // 16 MB
    __bf16*    AOb = (__bf16*)(ws + 56 * MB);    // 8 MB (total 64 MB)

    // 1. casts (2 dispatches)
    cast_f32_bf16<<<4096, 256, 0, stream>>>(x, xb, MTOT * DIM);
    cast_w4<<<dim3(1024, 4), 256, 0, stream>>>(Wq, Wk, Wv, Wo, Wqb, Wkb, Wvb, Wob, DIM * DIM);

    // 2. fused QKV projection (+ V transpose), grid 1536
    qkv_gemm<<<dim3(48, 32), 256, 0, stream>>>(xb, Wqb, Wkb, Wvb, bq, bk, bv, Qb, Kb, VtH);

    // 3. head-sum denominators, grid 1024
    den3<<<dim3(S_LEN / 128, S_LEN / 64, 2), 256, 0, stream>>>(Qb, Kb, rd);

    // 4. attention, grid 1024
    attn3<<<dim3(S_LEN / 64, NH, 2), 256, 0, stream>>>(Qb, Kb, VtH, rd, AOb);

    // 5. output projection -> fp32 d_out, grid 512
    gemm_out<<<dim3(DIM / 64, MTOT / 128), 256, 0, stream>>>(AOb, Wob, bo, out);
}